// Round 11
// baseline (625.447 us; speedup 1.0000x reference)
//
#include <hip/hip_runtime.h>
#include <hip/hip_bf16.h>

#define B_  1024
#define L_  64
#define E_  1024
#define DC_ 768
#define N_  16384
#define NZ_ 16                      // K-split slices for readout GEMM

typedef short bf16x8 __attribute__((ext_vector_type(8)));
typedef float f32x4  __attribute__((ext_vector_type(4)));
typedef float f32x16 __attribute__((ext_vector_type(16)));

// ---------------- ws layout (bytes) ----------------
// Xb       : 0          1024*768*2            = 1,572,864
// CBb      : 1572864    16384*768*2           = 25,165,824
// CBt      : 26738688   768*16384*2           = 25,165,824
// P        : 51904512   1024*16384*2          = 33,554,432
//   inb    : 51904512   (overlaps P) dead before P written
//   pwb    : 54001664   (overlaps P)
// cluePart : 85458944   16*1024*768*4         = 50,331,648
// clueF    : 135790592  1024*768*4            = 3,145,728
// rX       : 138936320  4096
// rW       : 138940416  65536
// Z        : 139005952  4096
// vl       : 139010048  4096
// flag     : 139014144  4

// ---- mask layout detection: 1 = int32 0/1, 2 = float32 0/1, 0 = bytes ----
__global__ void detect_mask(const unsigned int* __restrict__ mi, int* __restrict__ flag) {
    __shared__ int notInt, notFlt;
    if (threadIdx.x == 0) { notInt = 0; notFlt = 0; }
    __syncthreads();
    int ni = 0, nf = 0;
    for (int i = threadIdx.x; i < 16384; i += 256) {
        unsigned v = mi[i];
        if (v > 1u) ni = 1;
        if (v != 0u && v != 0x3f800000u) nf = 1;
    }
    if (ni) notInt = 1;
    if (nf) notFlt = 1;
    __syncthreads();
    if (threadIdx.x == 0) *flag = (!notInt) ? 1 : ((!notFlt) ? 2 : 0);
}

__global__ void compute_vl(const void* __restrict__ mask, const int* __restrict__ flag,
                           int* __restrict__ vl) {
    int b = blockIdx.x * blockDim.x + threadIdx.x;
    if (b >= B_) return;
    int f = *flag;
    int s = 0;
    if (f == 1) {
        const int* m = (const int*)mask;
        for (int j = 0; j < L_; ++j) s += m[b * L_ + j];
    } else if (f == 2) {
        const float* m = (const float*)mask;
        for (int j = 0; j < L_; ++j) s += (m[b * L_ + j] != 0.0f) ? 1 : 0;
    } else {
        const unsigned char* m = (const unsigned char*)mask;
        for (int j = 0; j < L_; ++j) s += m[b * L_ + j];
    }
    vl[b] = L_ - s;
}

// ---- row inverse-norm (fp32 source) ----
__global__ __launch_bounds__(256) void rownorm(const float* __restrict__ M,
                                               float* __restrict__ r, int cols) {
    int row = blockIdx.x;
    const float* p = M + (size_t)row * cols;
    float s = 0.0f;
    for (int c = threadIdx.x; c < cols; c += 256) { float v = p[c]; s += v * v; }
    for (int off = 32; off > 0; off >>= 1) s += __shfl_down(s, off);
    __shared__ float sm[4];
    if ((threadIdx.x & 63) == 0) sm[threadIdx.x >> 6] = s;
    __syncthreads();
    if (threadIdx.x == 0) {
        float t = sm[0] + sm[1] + sm[2] + sm[3];
        r[row] = 1.0f / fmaxf(sqrtf(t), 1e-8f);
    }
}

// ---- row inverse-norm (bf16 source) ----
__global__ __launch_bounds__(256) void rownorm_bf16(const __hip_bfloat16* __restrict__ M,
                                                    float* __restrict__ r, int cols) {
    int row = blockIdx.x;
    const __hip_bfloat16* p = M + (size_t)row * cols;
    float s = 0.0f;
    for (int c = threadIdx.x; c < cols; c += 256) { float v = __bfloat162float(p[c]); s += v * v; }
    for (int off = 32; off > 0; off >>= 1) s += __shfl_down(s, off);
    __shared__ float sm[4];
    if ((threadIdx.x & 63) == 0) sm[threadIdx.x >> 6] = s;
    __syncthreads();
    if (threadIdx.x == 0) {
        float t = sm[0] + sm[1] + sm[2] + sm[3];
        r[row] = 1.0f / fmaxf(sqrtf(t), 1e-8f);
    }
}

// ---- codebook prep: CBb = bf16(CB) [n][k]; CBt = bf16(CB)^T [d][n] ----
__global__ __launch_bounds__(256) void prep_cb(const float* __restrict__ CB,
                                               __hip_bfloat16* __restrict__ CBb,
                                               __hip_bfloat16* __restrict__ CBt) {
    __shared__ float t[64][65];
    int n0 = blockIdx.x * 64, d0 = blockIdx.y * 64;
    int tid = threadIdx.x;
    #pragma unroll
    for (int i = 0; i < 16; ++i) {
        int r = (tid >> 6) + i * 4, c = tid & 63;
        float v = CB[(size_t)(n0 + r) * DC_ + d0 + c];
        t[r][c] = v;
        CBb[(size_t)(n0 + r) * DC_ + d0 + c] = __float2bfloat16(v);
    }
    __syncthreads();
    #pragma unroll
    for (int i = 0; i < 16; ++i) {
        int r = (tid >> 6) + i * 4, c = tid & 63;
        CBt[(size_t)(d0 + r) * N_ + n0 + c] = __float2bfloat16(t[c][r]);
    }
}

// ---- elementwise fp32 -> bf16 cast (vectorized), n divisible by 4 ----
__global__ __launch_bounds__(256) void cast_bf16(const float* __restrict__ src,
                                                 ushort* __restrict__ dst, int n4) {
    int idx = blockIdx.x * 256 + threadIdx.x;
    if (idx >= n4) return;
    float4 v = ((const float4*)src)[idx];
    ushort4 o;
    __hip_bfloat16 h0 = __float2bfloat16(v.x); o.x = __builtin_bit_cast(ushort, h0);
    __hip_bfloat16 h1 = __float2bfloat16(v.y); o.y = __builtin_bit_cast(ushort, h1);
    __hip_bfloat16 h2 = __float2bfloat16(v.z); o.z = __builtin_bit_cast(ushort, h2);
    __hip_bfloat16 h3 = __float2bfloat16(v.w); o.w = __builtin_bit_cast(ushort, h3);
    ((ushort4*)dst)[idx] = o;
}

// ======== 16x16x32 machinery (BK=32) — kept for proj (validated r5) ========
__device__ __forceinline__ void stage_tile(const __hip_bfloat16* __restrict__ src, size_t ldk,
                                           __hip_bfloat16* smem, int wave, int lane) {
    #pragma unroll
    for (int s = 0; s < 2; ++s) {
        const int chunk = wave * 32 + s * 16;
        const int r = chunk + (lane >> 2);
        const int gslot = (lane & 3) ^ ((lane >> 2) & 3);
        const __hip_bfloat16* g = src + (size_t)r * ldk + gslot * 8;
        __builtin_amdgcn_global_load_lds(
            (const __attribute__((address_space(1))) void*)g,
            (__attribute__((address_space(3))) void*)(smem + chunk * 32), 16, 0, 0);
    }
}

__device__ __forceinline__ bf16x8 read_frag(const __hip_bfloat16* smem, int base_row, int lane) {
    const int r = base_row + (lane & 15);
    const int slot = ((lane >> 4) ^ r) & 3;
    return *(const bf16x8*)(smem + r * 32 + slot * 8);
}

// ---- proj: Xb[m][d] = bf16( inb[m]·pwb[d] + bias[d] ), 16x16 path ----
__global__ __launch_bounds__(256) void proj_mfma(const __hip_bfloat16* __restrict__ inb,
                                                 const __hip_bfloat16* __restrict__ pwb,
                                                 const float* __restrict__ bias,
                                                 __hip_bfloat16* __restrict__ Xb) {
    __shared__ __align__(16) __hip_bfloat16 As[128 * 32];
    __shared__ __align__(16) __hip_bfloat16 Bs[128 * 32];
    const int t = threadIdx.x, lane = t & 63, wave = t >> 6;
    const int wr = wave >> 1, wc = wave & 1;
    const int m0 = blockIdx.y * 128, n0 = blockIdx.x * 128;

    f32x4 acc[4][4];
    #pragma unroll
    for (int i = 0; i < 4; ++i)
        #pragma unroll
        for (int j = 0; j < 4; ++j) acc[i][j] = (f32x4){0.f, 0.f, 0.f, 0.f};

    const __hip_bfloat16* Asrc = inb + (size_t)m0 * E_;
    const __hip_bfloat16* Bsrc = pwb + (size_t)n0 * E_;
    for (int k0 = 0; k0 < E_; k0 += 32) {
        stage_tile(Asrc + k0, E_, As, wave, lane);
        stage_tile(Bsrc + k0, E_, Bs, wave, lane);
        __syncthreads();
        bf16x8 af[4], bg[4];
        #pragma unroll
        for (int i = 0; i < 4; ++i) af[i] = read_frag(As, wr * 64 + i * 16, lane);
        #pragma unroll
        for (int j = 0; j < 4; ++j) bg[j] = read_frag(Bs, wc * 64 + j * 16, lane);
        #pragma unroll
        for (int i = 0; i < 4; ++i)
            #pragma unroll
            for (int j = 0; j < 4; ++j)
                acc[i][j] = __builtin_amdgcn_mfma_f32_16x16x32_bf16(af[i], bg[j], acc[i][j], 0, 0, 0);
        __syncthreads();
    }

    const int fr = lane & 15, fq = lane >> 4;
    #pragma unroll
    for (int i = 0; i < 4; ++i) {
        const int mb = m0 + wr * 64 + i * 16 + fq * 4;
        #pragma unroll
        for (int j = 0; j < 4; ++j) {
            const int d = n0 + wc * 64 + j * 16 + fr;
            const float bv = bias[d];
            #pragma unroll
            for (int q = 0; q < 4; ++q)
                Xb[(size_t)(mb + q) * DC_ + d] = __float2bfloat16(acc[i][j][q] + bv);
        }
    }
}

// ======== 32x32x16 machinery (BK=64) for the two big GEMMs ========
// LDS [128 rows][8 slots of 8 bf16] (row = 128 B). Slot XOR-swizzled by (row&7):
// LDS[r][s] = global[r][s ^ (r&7)], achieved with linear global_load_lds dest +
// inverse-swizzled global source (rule #21). Reads undo via the same XOR.
__device__ __forceinline__ void stage64(const __hip_bfloat16* __restrict__ src, size_t ldk,
                                        __hip_bfloat16* smem, int wave, int lane) {
    #pragma unroll
    for (int s = 0; s < 4; ++s) {
        const int rowbase = wave * 32 + s * 8;
        const int r = rowbase + (lane >> 3);
        const int gslot = (lane & 7) ^ ((lane >> 3) & 7);
        const __hip_bfloat16* g = src + (size_t)r * ldk + gslot * 8;
        __builtin_amdgcn_global_load_lds(
            (const __attribute__((address_space(1))) void*)g,
            (__attribute__((address_space(3))) void*)(smem + rowbase * 64), 16, 0, 0);
    }
}

// A/B fragment for mfma_32x32x16: row = base_row + (lane&31), k-chunk = lane>>5,
// logical slot = khalf*2 + (lane>>5), physical = logical ^ (row&7).
__device__ __forceinline__ bf16x8 read_frag32(const __hip_bfloat16* smem, int base_row,
                                              int khalf, int lane) {
    const int r = base_row + (lane & 31);
    const int slot = (khalf * 2 + (lane >> 5)) ^ (r & 7);
    return *(const bf16x8*)(smem + r * 64 + slot * 8);
}

// ---- score: P[m][n] = bf16(exp(-(Xb[m]·CBb[n])*rX[m]*rW[n])), Z[m] += rowsum ----
__global__ __launch_bounds__(256) void score_mfma(const __hip_bfloat16* __restrict__ Xb,
                                                  const __hip_bfloat16* __restrict__ CBb,
                                                  const float* __restrict__ rX,
                                                  const float* __restrict__ rW,
                                                  __hip_bfloat16* __restrict__ P,
                                                  float* __restrict__ Z) {
    __shared__ __align__(16) __hip_bfloat16 As[128 * 64];
    __shared__ __align__(16) __hip_bfloat16 Bs[128 * 64];
    const int t = threadIdx.x, lane = t & 63, wave = t >> 6;
    const int wr = wave >> 1, wc = wave & 1;
    const int m0 = blockIdx.y * 128, n0 = blockIdx.x * 128;

    f32x16 acc[2][2];
    #pragma unroll
    for (int i = 0; i < 2; ++i)
        #pragma unroll
        for (int j = 0; j < 2; ++j) acc[i][j] = (f32x16)(0.f);

    const __hip_bfloat16* Asrc = Xb  + (size_t)m0 * DC_;
    const __hip_bfloat16* Bsrc = CBb + (size_t)n0 * DC_;
    for (int k0 = 0; k0 < DC_; k0 += 64) {
        stage64(Asrc + k0, DC_, As, wave, lane);
        stage64(Bsrc + k0, DC_, Bs, wave, lane);
        __syncthreads();
        #pragma unroll
        for (int h = 0; h < 4; ++h) {
            bf16x8 a0 = read_frag32(As, wr * 64,      h, lane);
            bf16x8 a1 = read_frag32(As, wr * 64 + 32, h, lane);
            bf16x8 b0 = read_frag32(Bs, wc * 64,      h, lane);
            bf16x8 b1 = read_frag32(Bs, wc * 64 + 32, h, lane);
            acc[0][0] = __builtin_amdgcn_mfma_f32_32x32x16_bf16(a0, b0, acc[0][0], 0, 0, 0);
            acc[0][1] = __builtin_amdgcn_mfma_f32_32x32x16_bf16(a0, b1, acc[0][1], 0, 0, 0);
            acc[1][0] = __builtin_amdgcn_mfma_f32_32x32x16_bf16(a1, b0, acc[1][0], 0, 0, 0);
            acc[1][1] = __builtin_amdgcn_mfma_f32_32x32x16_bf16(a1, b1, acc[1][1], 0, 0, 0);
        }
        __syncthreads();
    }

    // C/D map: col = lane&31, row = (r&3) + 8*(r>>2) + 4*(lane>>5)
    const int col = lane & 31, hi = lane >> 5;
    float rwj[2];
    #pragma unroll
    for (int j = 0; j < 2; ++j) rwj[j] = rW[n0 + wc * 64 + j * 32 + col];
    #pragma unroll
    for (int i = 0; i < 2; ++i) {
        float rs[16];
        #pragma unroll
        for (int r = 0; r < 16; ++r) rs[r] = 0.f;
        #pragma unroll
        for (int r = 0; r < 16; ++r) {
            const int m = m0 + wr * 64 + i * 32 + (r & 3) + 8 * (r >> 2) + 4 * hi;
            const float rx = rX[m];
            #pragma unroll
            for (int j = 0; j < 2; ++j) {
                const int n = n0 + wc * 64 + j * 32 + col;
                float e = __expf(-acc[i][j][r] * rx * rwj[j]);
                P[(size_t)m * N_ + n] = __float2bfloat16(e);
                rs[r] += e;
            }
        }
        #pragma unroll
        for (int r = 0; r < 16; ++r) {
            float s = rs[r];
            s += __shfl_xor(s, 1);  s += __shfl_xor(s, 2);
            s += __shfl_xor(s, 4);  s += __shfl_xor(s, 8);
            s += __shfl_xor(s, 16);
            if (col == 0) {
                const int m = m0 + wr * 64 + i * 32 + (r & 3) + 8 * (r >> 2) + 4 * hi;
                atomicAdd(&Z[m], s);
            }
        }
    }
}

// ---- readout: cluePart[z][m][d] = sum_{n in slice z} P[m][n]*CBt[d][n] ----
// grid (x = m-blocks, y = d-blocks, z = NZ): blocks sharing a P A-tile are 8
// apart in flat id -> same XCD -> L2-local A reads. Plain stores, no atomics.
__global__ __launch_bounds__(256) void out_mfma(const __hip_bfloat16* __restrict__ P,
                                                const __hip_bfloat16* __restrict__ CBt,
                                                float* __restrict__ cluePart) {
    __shared__ __align__(16) __hip_bfloat16 As[128 * 64];
    __shared__ __align__(16) __hip_bfloat16 Bs[128 * 64];
    const int t = threadIdx.x, lane = t & 63, wave = t >> 6;
    const int wr = wave >> 1, wc = wave & 1;
    const int m0 = blockIdx.x * 128, d0 = blockIdx.y * 128;
    const int kbeg = blockIdx.z * (N_ / NZ_);
    float* outp = cluePart + (size_t)blockIdx.z * (B_ * DC_);

    f32x16 acc[2][2];
    #pragma unroll
    for (int i = 0; i < 2; ++i)
        #pragma unroll
        for (int j = 0; j < 2; ++j) acc[i][j] = (f32x16)(0.f);

    const __hip_bfloat16* Asrc = P   + (size_t)m0 * N_;
    const __hip_bfloat16* Bsrc = CBt + (size_t)d0 * N_;
    for (int kk = 0; kk < N_ / NZ_; kk += 64) {
        const int k0 = kbeg + kk;
        stage64(Asrc + k0, N_, As, wave, lane);
        stage64(Bsrc + k0, N_, Bs, wave, lane);
        __syncthreads();
        #pragma unroll
        for (int h = 0; h < 4; ++h) {
            bf16x8 a0 = read_frag32(As, wr * 64,      h, lane);
            bf16x8 a1 = read_frag32(As, wr * 64 + 32, h, lane);
            bf16x8 b0 = read_frag32(Bs, wc * 64,      h, lane);
            bf16x8 b1 = read_frag32(Bs, wc * 64 + 32, h, lane);
            acc[0][0] = __builtin_amdgcn_mfma_f32_32x32x16_bf16(a0, b0, acc[0][0], 0, 0, 0);
            acc[0][1] = __builtin_amdgcn_mfma_f32_32x32x16_bf16(a0, b1, acc[0][1], 0, 0, 0);
            acc[1][0] = __builtin_amdgcn_mfma_f32_32x32x16_bf16(a1, b0, acc[1][0], 0, 0, 0);
            acc[1][1] = __builtin_amdgcn_mfma_f32_32x32x16_bf16(a1, b1, acc[1][1], 0, 0, 0);
        }
        __syncthreads();
    }

    const int col = lane & 31, hi = lane >> 5;
    #pragma unroll
    for (int i = 0; i < 2; ++i)
        #pragma unroll
        for (int r = 0; r < 16; ++r) {
            const int m = m0 + wr * 64 + i * 32 + (r & 3) + 8 * (r >> 2) + 4 * hi;
            #pragma unroll
            for (int j = 0; j < 2; ++j) {
                const int d = d0 + wc * 64 + j * 32 + col;
                outp[(size_t)m * DC_ + d] = acc[i][j][r];
            }
        }
}

// ---- reduce partials + normalize: clueF[b][d] = (sum_z cluePart[z][b][d]) / Z[b] ----
__global__ __launch_bounds__(256) void reduce_clue(const float* __restrict__ cluePart,
                                                   const float* __restrict__ Z,
                                                   float* __restrict__ clueF) {
    const int d = blockIdx.x * 256 + threadIdx.x;
    const int b = blockIdx.y;
    float s = 0.0f;
    #pragma unroll
    for (int z = 0; z < NZ_; ++z)
        s += cluePart[(size_t)z * (B_ * DC_) + (size_t)b * DC_ + d];
    clueF[(size_t)b * DC_ + d] = s / Z[b];
}

// ---- assemble new_text_emb (float4 copy with row substitution) ----
__global__ __launch_bounds__(256) void assemble(const float* __restrict__ text,
                                                const float* __restrict__ clueF,
                                                const int* __restrict__ vl,
                                                float* __restrict__ out) {
    int idx = blockIdx.x * 256 + threadIdx.x;
    int c = idx % 192;
    int bl = idx / 192;
    int l = bl & 63, b = bl >> 6;
    int v = vl[b];
    float4 val;
    if (l == v) {
        val = ((const float4*)text)[(size_t)(b * 64 + v - 1) * 192 + c];
    } else if (l == v - 1) {
        val = ((const float4*)(clueF + (size_t)b * DC_))[c];
    } else {
        val = ((const float4*)text)[idx];
    }
    ((float4*)out)[idx] = val;
}

// ---- mask output (float 0/1) + scalar 0 ----
__global__ void mask_scalar(const int* __restrict__ vl, float* __restrict__ out_mask,
                            float* __restrict__ out_scalar) {
    int idx = blockIdx.x * blockDim.x + threadIdx.x;
    if (idx < B_ * L_) {
        int b = idx >> 6, j = idx & 63;
        out_mask[idx] = (j > vl[b]) ? 1.0f : 0.0f;
    }
    if (idx == 0) *out_scalar = 0.0f;
}

extern "C" void kernel_launch(void* const* d_in, const int* in_sizes, int n_in,
                              void* d_out, int out_size, void* d_ws, size_t ws_size,
                              hipStream_t stream) {
    const float* inputs  = (const float*)d_in[0];
    const float* text    = (const float*)d_in[1];
    const void*  mask    = d_in[2];
    const float* proj_w  = (const float*)d_in[3];
    const float* proj_b  = (const float*)d_in[4];
    const float* codebook= (const float*)d_in[5];
    float* out = (float*)d_out;

    char* ws = (char*)d_ws;
    __hip_bfloat16* Xb       = (__hip_bfloat16*)(ws + 0);
    __hip_bfloat16* CBb      = (__hip_bfloat16*)(ws + 1572864);
    __hip_bfloat16* CBt      = (__hip_bfloat16*)(ws + 26738688);
    __hip_bfloat16* P        = (__hip_bfloat16*)(ws + 51904512);
    __hip_bfloat16* inb      = (__hip_bfloat16*)(ws + 51904512);           // overlaps P
    __hip_bfloat16* pwb      = (__hip_bfloat16*)(ws + 54001664);           // overlaps P
    float*          cluePart = (float*)(ws + 85458944);
    float*          clueF    = (float*)(ws + 135790592);
    float*          rX       = (float*)(ws + 138936320);
    float*          rW       = (float*)(ws + 138940416);
    float*          Z        = (float*)(ws + 139005952);
    int*            vl       = (int*)(ws + 139010048);
    int*            flag     = (int*)(ws + 139014144);

    hipMemsetAsync(Z, 0, B_ * sizeof(float), stream);

    detect_mask<<<1, 256, 0, stream>>>((const unsigned int*)mask, flag);
    compute_vl<<<4, 256, 0, stream>>>(mask, flag, vl);
    rownorm<<<N_, 256, 0, stream>>>(codebook, rW, DC_);
    prep_cb<<<dim3(N_ / 64, DC_ / 64), 256, 0, stream>>>(codebook, CBb, CBt);
    cast_bf16<<<(B_ * E_ / 4 + 255) / 256, 256, 0, stream>>>(inputs, (ushort*)inb, B_ * E_ / 4);
    cast_bf16<<<(DC_ * E_ / 4 + 255) / 256, 256, 0, stream>>>(proj_w, (ushort*)pwb, DC_ * E_ / 4);
    proj_mfma<<<dim3(DC_ / 128, B_ / 128), 256, 0, stream>>>(inb, pwb, proj_b, Xb);
    rownorm_bf16<<<B_, 256, 0, stream>>>(Xb, rX, DC_);
    score_mfma<<<dim3(N_ / 128, B_ / 128), 256, 0, stream>>>(Xb, CBb, rX, rW, P, Z);
    out_mfma<<<dim3(B_ / 128, DC_ / 128, NZ_), 256, 0, stream>>>(P, CBt, cluePart);
    reduce_clue<<<dim3(DC_ / 256, B_), 256, 0, stream>>>(cluePart, Z, clueF);
    assemble<<<49152, 256, 0, stream>>>(text, clueF, vl, out);
    mask_scalar<<<(B_ * L_ + 255) / 256, 256, 0, stream>>>(
        vl, out + (size_t)B_ * L_ * DC_, out + (size_t)B_ * L_ * DC_ + B_ * L_);
}